// Round 9
// baseline (124.780 us; speedup 1.0000x reference)
//
#include <hip/hip_runtime.h>

// SepConv on sphere, round 9: ONE kernel, fat pipelined blocks.
// Algebra (verified absmax 0.0 since R2): the chain
//   x -> *qw -> DISCO(K=4,9tap) -> depth-mix -> *qw -> DISCO(K=1,4tap) -> 1x1
// composes into one 5x5 clip/wrap stencil with per-(c,h) coefs
// C[c][25] = w_depth[c,:] . S[4][25] (144 composed taps per row), then a
// 32->64 pointwise GEMV.
//
// R9: block = (row h, PAIR of 64-px segments), grid (184,3)=552 blocks.
// Prologue amortized over 2 tiles; tile-1 global loads issued before tile-0's
// GEMV (double-buffered LDS zs[2]) so the load latency hides behind ~1000
// VALU cycles — attacks the issue-starvation seen in R5/R8 counters
// (VALUBusy ~14%, occ ~27%, all pipes idle).

#define H_    181
#define W_    360
#define CIN_  32
#define COUT_ 64
#define K_    4
#define NNZ_  9
#define NNZ1_ 4
#define HW_   (H_*W_)
#define NT_   (NNZ1_*K_*NNZ_)   // 144 composed taps per output row

__global__ __launch_bounds__(256) void sepconv_one(
    const float* __restrict__ x, const float* __restrict__ quad_w,
    const float* __restrict__ vals, const int* __restrict__ hi,
    const int* __restrict__ wi, const float* __restrict__ w_depth,
    const float* __restrict__ vals1, const int* __restrict__ hi1,
    const int* __restrict__ wi1, const float* __restrict__ w_point,
    const float* __restrict__ bias, float* __restrict__ out)
{
    const int bx = blockIdx.x;
    const int h  = (bx & 7) * 23 + (bx >> 3);   // XCD-contiguous row bands
    if (h >= H_) return;                         // 3 pad rows, uniform exit
    const int sp  = blockIdx.y;                  // segment pair 0..2
    const int tid = threadIdx.x;

    __shared__ float Tval[NT_];
    __shared__ int   Tbin[NT_];
    __shared__ float S[K_][25];
    __shared__ float C[CIN_][25];
    __shared__ float zs[2][64][33];   // double-buffered z tile, <=2-way banks

    // --- coef prologue (parallel, once per block) ---------------------------
    if (tid < NT_) {
        const int a   = tid / 36;
        const int rem = tid - a * 36;
        const int k   = rem / 9;
        const int j   = rem - k * 9;
        const int e1  = h * NNZ1_ + a;
        const int m   = hi1[e1];
        const int w1  = wi1[e1];
        const int d1  = (w1 == 1) ? 1 : ((w1 == 0) ? 0 : -1);
        const int e   = (k * H_ + m) * NNZ_ + j;
        const int r   = hi[e];
        const int ww  = wi[e];
        const int d   = (ww == 1) ? 1 : ((ww == 0) ? 0 : -1);
        Tval[tid] = vals1[e1] * quad_w[m] * vals[e] * quad_w[r];
        Tbin[tid] = (r - h + 2) * 5 + (d1 + d + 2);   // in [0,25)
    }
    __syncthreads();

    if (tid < K_ * 25) {           // parallel read-only scans (broadcast LDS)
        const int k   = tid / 25;
        const int bin = tid - k * 25;
        float s = 0.f;
        #pragma unroll
        for (int a = 0; a < NNZ1_; ++a)
            #pragma unroll
            for (int j = 0; j < NNZ_; ++j) {
                const int t2 = a * 36 + k * 9 + j;
                if (Tbin[t2] == bin) s += Tval[t2];
            }
        S[k][bin] = s;
    }
    __syncthreads();

    for (int i = tid; i < CIN_ * 25; i += 256) {
        const int c = i / 25, bin = i - c * 25;
        float acc = 0.f;
        #pragma unroll
        for (int k = 0; k < K_; ++k) acc += w_depth[c * K_ + k] * S[k][bin];
        C[c][bin] = acc;
    }
    __syncthreads();

    int rowoff[5];
    #pragma unroll
    for (int rb = 0; rb < 5; ++rb) {
        int r = h - 2 + rb;
        r = (r < 0) ? 0 : ((r > H_ - 1) ? H_ - 1 : r);
        rowoff[rb] = r * W_;
    }

    // thread roles (fixed for both tiles):
    const int g  = tid & 15;          // 4-px group within 64-px tile
    const int c0 = tid >> 4;          // channel for item 0 (0..15)
    const int c1 = c0 + 16;           // channel for item 1
    const int j  = tid & 63;          // GEMV pixel lane
    const int oh = tid >> 6;          // GEMV o-quarter (wave-uniform)

    const int seg0 = sp * 2 + 0;
    const int seg1 = sp * 2 + 1;
    const int gn1  = (seg1 == 5) ? 10 : 16;   // tile1 may be the 40-px tail

    // loads for one (c, bw) item -> 15 float4 in registers
    auto load_item = [&](int c, int bw, float4* Lv) {
        const int cA = (bw + W_ - 4) % W_;
        const int cB = bw;
        const int cC = (bw + 4) % W_;
        const float* xc = x + c * HW_;
        #pragma unroll
        for (int rb = 0; rb < 5; ++rb) {
            const float* xr = xc + rowoff[rb];
            Lv[rb * 3 + 0] = *(const float4*)(xr + cA);
            Lv[rb * 3 + 1] = *(const float4*)(xr + cB);
            Lv[rb * 3 + 2] = *(const float4*)(xr + cC);
        }
    };
    // FMA reduction for one item -> 4 pixel results
    auto fma_item = [&](int c, const float4* Lv, float* a) {
        const float* Cc = &C[c][0];
        a[0] = a[1] = a[2] = a[3] = 0.f;
        #pragma unroll
        for (int rb = 0; rb < 5; ++rb) {
            const float4 vA = Lv[rb * 3 + 0];
            const float4 vB = Lv[rb * 3 + 1];
            const float4 vC = Lv[rb * 3 + 2];
            const float k0 = Cc[rb * 5 + 0], k1 = Cc[rb * 5 + 1],
                        k2 = Cc[rb * 5 + 2], k3 = Cc[rb * 5 + 3],
                        k4 = Cc[rb * 5 + 4];
            a[0] += k0 * vA.z + k1 * vA.w + k2 * vB.x + k3 * vB.y + k4 * vB.z;
            a[1] += k0 * vA.w + k1 * vB.x + k2 * vB.y + k3 * vB.z + k4 * vB.w;
            a[2] += k0 * vB.x + k1 * vB.y + k2 * vB.z + k3 * vB.w + k4 * vC.x;
            a[3] += k0 * vB.y + k1 * vB.z + k2 * vB.w + k3 * vC.x + k4 * vC.y;
        }
    };
    auto gemv = [&](int t, int seg) {
        const int w0  = seg * 64;
        const int pxn = (seg == 5) ? 40 : 64;
        if (j < pxn) {
            float zr[CIN_];
            #pragma unroll
            for (int c = 0; c < CIN_; ++c) zr[c] = zs[t][j][c];  // 2-way, free
            const float* wp = w_point + oh * 16 * CIN_;          // s_loads
            float* op = out + oh * 16 * HW_ + h * W_ + w0 + j;
            #pragma unroll 4
            for (int oo = 0; oo < 16; ++oo) {
                float acc = bias[oh * 16 + oo];
                #pragma unroll
                for (int c = 0; c < CIN_; ++c)
                    acc += wp[oo * CIN_ + c] * zr[c];
                op[oo * HW_] = acc;          // 256B contiguous per wave
            }
        }
    };

    // --- Tile 0 Phase A ------------------------------------------------------
    {
        const int bw = seg0 * 64 + g * 4;
        float4 L0[15], L1[15];
        load_item(c0, bw, L0);
        load_item(c1, bw, L1);
        float a0[4], a1[4];
        fma_item(c0, L0, a0);
        fma_item(c1, L1, a1);
        const int p = g * 4;
        #pragma unroll
        for (int u = 0; u < 4; ++u) {
            zs[0][p + u][c0] = a0[u];
            zs[0][p + u][c1] = a1[u];
        }
    }
    __syncthreads();                  // zs[0] ready

    // --- Pipeline: tile-1 loads in flight during tile-0 GEMV ----------------
    float4 P0[15], P1[15];
    const bool act1 = (g < gn1);
    const int  bw1  = seg1 * 64 + g * 4;
    if (act1) {
        load_item(c0, bw1, P0);       // issued here; consumed after gemv(0)
        load_item(c1, bw1, P1);
    }

    gemv(0, seg0);                    // ~1000 VALU cycles hide the loads

    if (act1) {
        float a0[4], a1[4];
        fma_item(c0, P0, a0);
        fma_item(c1, P1, a1);
        const int p = g * 4;
        #pragma unroll
        for (int u = 0; u < 4; ++u) {
            zs[1][p + u][c0] = a0[u];
            zs[1][p + u][c1] = a1[u];
        }
    }
    __syncthreads();                  // zs[1] ready

    gemv(1, seg1);
}

extern "C" void kernel_launch(void* const* d_in, const int* in_sizes, int n_in,
                              void* d_out, int out_size, void* d_ws, size_t ws_size,
                              hipStream_t stream) {
    const float* x       = (const float*)d_in[0];
    const float* quad_w  = (const float*)d_in[1];
    const float* vals    = (const float*)d_in[2];
    // d_in[3] = seg  (unused; tap membership implied by entry ordering)
    const int*   hi      = (const int*)d_in[4];
    const int*   wi      = (const int*)d_in[5];
    const float* w_depth = (const float*)d_in[6];
    const float* vals1   = (const float*)d_in[7];
    // d_in[8] = seg1 (unused)
    const int*   hi1     = (const int*)d_in[9];
    const int*   wi1     = (const int*)d_in[10];
    const float* w_point = (const float*)d_in[11];
    const float* bias    = (const float*)d_in[12];
    // d_in[13] = K (compile-time constant 4)

    sepconv_one<<<dim3(184, 3), 256, 0, stream>>>(
        x, quad_w, vals, hi, wi, w_depth, vals1, hi1, wi1,
        w_point, bias, (float*)d_out);
}

// Round 10
// 115.963 us; speedup vs baseline: 1.0760x; 1.0760x over previous
//
#include <hip/hip_runtime.h>

// SepConv on sphere, round 10: ONE kernel, load-first pipelined blocks.
// Algebra (verified absmax 0.0 since R2): the chain
//   x -> *qw -> DISCO(K=4,9tap) -> depth-mix -> *qw -> DISCO(K=1,4tap) -> 1x1
// composes into one 5x5 clip/wrap stencil with per-(c,h) coefs
// C[c][25] = w_depth[c,:] . S[4][25] (144 composed taps per row), then a
// 32->64 pointwise GEMV.
//
// R10 vs R8: 512-thread blocks (one stencil item per thread: 32ch x 16grp),
// and the 15 float4 x-loads are ISSUED BEFORE the 3-barrier coef prologue so
// their latency drains behind it (addresses don't depend on taps). R9's
// regression (VGPR 104, occ 12.7%, 69k conflicts) is reverted.

#define H_    181
#define W_    360
#define CIN_  32
#define COUT_ 64
#define K_    4
#define NNZ_  9
#define NNZ1_ 4
#define HW_   (H_*W_)
#define NT_   (NNZ1_*K_*NNZ_)   // 144 composed taps per output row

__global__ __launch_bounds__(512) void sepconv_one(
    const float* __restrict__ x, const float* __restrict__ quad_w,
    const float* __restrict__ vals, const int* __restrict__ hi,
    const int* __restrict__ wi, const float* __restrict__ w_depth,
    const float* __restrict__ vals1, const int* __restrict__ hi1,
    const int* __restrict__ wi1, const float* __restrict__ w_point,
    const float* __restrict__ bias, float* __restrict__ out)
{
    const int bx = blockIdx.x;
    const int h  = (bx & 7) * 23 + (bx >> 3);   // XCD-contiguous row bands
    if (h >= H_) return;                         // 3 pad rows, uniform exit
    const int seg = blockIdx.y;                  // 0..5
    const int w0  = seg * 64;
    const int pxn = (seg == 5) ? 40 : 64;        // 360 = 5*64 + 40
    const int gn  = pxn >> 2;
    const int tid = threadIdx.x;

    __shared__ float Tval[NT_];
    __shared__ int   Tbin[NT_];
    __shared__ float S[K_][25];
    __shared__ float C[CIN_][25];
    __shared__ float zs[64][33];   // [px][ch]; <=2-way banks everywhere (free)

    // --- x prefetch FIRST: addresses independent of taps --------------------
    // thread = (c = tid>>4 in 0..31, g = tid&15): one 4-px stencil item.
    const int g = tid & 15;
    const int c = tid >> 4;
    const bool act = (g < gn);

    int rowoff[5];
    #pragma unroll
    for (int rb = 0; rb < 5; ++rb) {
        int r = h - 2 + rb;
        r = (r < 0) ? 0 : ((r > H_ - 1) ? H_ - 1 : r);
        rowoff[rb] = r * W_;
    }

    const int bw = w0 + g * 4;
    const int cA = (bw + W_ - 4) % W_;
    const int cB = bw;
    const int cC = (bw + 4) % W_;

    float4 L[15];
    if (act) {
        const float* xc = x + c * HW_;
        #pragma unroll
        for (int rb = 0; rb < 5; ++rb) {
            const float* xr = xc + rowoff[rb];
            L[rb * 3 + 0] = *(const float4*)(xr + cA);   // in flight during
            L[rb * 3 + 1] = *(const float4*)(xr + cB);   // the prologue below
            L[rb * 3 + 2] = *(const float4*)(xr + cC);
        }
    }

    // --- coef prologue (parallel; overlaps the x-load drain) ----------------
    if (tid < NT_) {
        const int a   = tid / 36;
        const int rem = tid - a * 36;
        const int k   = rem / 9;
        const int j   = rem - k * 9;
        const int e1  = h * NNZ1_ + a;
        const int m   = hi1[e1];
        const int w1  = wi1[e1];
        const int d1  = (w1 == 1) ? 1 : ((w1 == 0) ? 0 : -1);
        const int e   = (k * H_ + m) * NNZ_ + j;
        const int r   = hi[e];
        const int ww  = wi[e];
        const int d   = (ww == 1) ? 1 : ((ww == 0) ? 0 : -1);
        Tval[tid] = vals1[e1] * quad_w[m] * vals[e] * quad_w[r];
        Tbin[tid] = (r - h + 2) * 5 + (d1 + d + 2);   // in [0,25)
    }
    __syncthreads();

    if (tid < K_ * 25) {           // parallel read-only scans (broadcast LDS)
        const int k   = tid / 25;
        const int bin = tid - k * 25;
        float s = 0.f;
        #pragma unroll
        for (int a = 0; a < NNZ1_; ++a)
            #pragma unroll
            for (int j = 0; j < NNZ_; ++j) {
                const int t2 = a * 36 + k * 9 + j;
                if (Tbin[t2] == bin) s += Tval[t2];
            }
        S[k][bin] = s;
    }
    __syncthreads();

    if (tid < CIN_ * 25) {         // 800 items, one per thread... 512: loop
        const int cc = tid / 25, bin = tid - cc * 25;
        float acc = 0.f;
        #pragma unroll
        for (int k = 0; k < K_; ++k) acc += w_depth[cc * K_ + k] * S[k][bin];
        C[cc][bin] = acc;
    }
    if (tid + 512 < CIN_ * 25) {
        const int i2 = tid + 512;
        const int cc = i2 / 25, bin = i2 - cc * 25;
        float acc = 0.f;
        #pragma unroll
        for (int k = 0; k < K_; ++k) acc += w_depth[cc * K_ + k] * S[k][bin];
        C[cc][bin] = acc;
    }
    __syncthreads();

    // --- Phase A: FMA on prefetched registers -> LDS z tile -----------------
    if (act) {
        const float* Cc = &C[c][0];
        float a0 = 0.f, a1 = 0.f, a2 = 0.f, a3 = 0.f;
        #pragma unroll
        for (int rb = 0; rb < 5; ++rb) {
            const float4 vA = L[rb * 3 + 0];
            const float4 vB = L[rb * 3 + 1];
            const float4 vC = L[rb * 3 + 2];
            const float k0 = Cc[rb * 5 + 0], k1 = Cc[rb * 5 + 1],
                        k2 = Cc[rb * 5 + 2], k3 = Cc[rb * 5 + 3],
                        k4 = Cc[rb * 5 + 4];
            a0 += k0 * vA.z + k1 * vA.w + k2 * vB.x + k3 * vB.y + k4 * vB.z;
            a1 += k0 * vA.w + k1 * vB.x + k2 * vB.y + k3 * vB.z + k4 * vB.w;
            a2 += k0 * vB.x + k1 * vB.y + k2 * vB.z + k3 * vB.w + k4 * vC.x;
            a3 += k0 * vB.y + k1 * vB.z + k2 * vB.w + k3 * vC.x + k4 * vC.y;
        }
        const int p = g * 4;
        zs[p + 0][c] = a0;      // bank (4g+u+c)%32: each hit 2x -> free
        zs[p + 1][c] = a1;
        zs[p + 2][c] = a2;
        zs[p + 3][c] = a3;
    }
    __syncthreads();

    // --- Phase B: 32->64 GEMV; thread = (px j, o-eighth oh) -----------------
    const int j  = tid & 63;
    const int oh = tid >> 6;            // 0..7, wave-uniform
    if (j < pxn) {
        float zr[CIN_];
        #pragma unroll
        for (int cc = 0; cc < CIN_; ++cc) zr[cc] = zs[j][cc];   // 2-way, free

        const float* wp = w_point + oh * 8 * CIN_;              // s_loads
        float* op = out + oh * 8 * HW_ + h * W_ + w0 + j;
        #pragma unroll
        for (int oo = 0; oo < 8; ++oo) {
            float acc = bias[oh * 8 + oo];
            #pragma unroll
            for (int cc = 0; cc < CIN_; ++cc)
                acc += wp[oo * CIN_ + cc] * zr[cc];
            op[oo * HW_] = acc;          // 256B contiguous per wave
        }
    }
}

extern "C" void kernel_launch(void* const* d_in, const int* in_sizes, int n_in,
                              void* d_out, int out_size, void* d_ws, size_t ws_size,
                              hipStream_t stream) {
    const float* x       = (const float*)d_in[0];
    const float* quad_w  = (const float*)d_in[1];
    const float* vals    = (const float*)d_in[2];
    // d_in[3] = seg  (unused; tap membership implied by entry ordering)
    const int*   hi      = (const int*)d_in[4];
    const int*   wi      = (const int*)d_in[5];
    const float* w_depth = (const float*)d_in[6];
    const float* vals1   = (const float*)d_in[7];
    // d_in[8] = seg1 (unused)
    const int*   hi1     = (const int*)d_in[9];
    const int*   wi1     = (const int*)d_in[10];
    const float* w_point = (const float*)d_in[11];
    const float* bias    = (const float*)d_in[12];
    // d_in[13] = K (compile-time constant 4)

    sepconv_one<<<dim3(184, 6), 512, 0, stream>>>(
        x, quad_w, vals, hi, wi, w_depth, vals1, hi1, wi1,
        w_point, bias, (float*)d_out);
}